// Round 18
// baseline (816.944 us; speedup 1.0000x reference)
//
#include <hip/hip_runtime.h>

#define NROWS 131072
#define KCB   2048
#define DIM   256
#define BUF   8192      // u16 per LDS buffer (16 KB)
#define SCR   16384     // u16 offset of epilogue scratch

typedef unsigned int u32;
typedef unsigned long long u64;
typedef unsigned short u16;
typedef __attribute__((ext_vector_type(8))) short short8;
typedef __attribute__((ext_vector_type(16))) float f32x16;

__device__ __forceinline__ u32 fkey(float f) {
    u32 b = __float_as_uint(f);
    return (b & 0x80000000u) ? ~b : (b | 0x80000000u);
}
__device__ __forceinline__ u16 bf_rne(float x) {
    u32 u = __float_as_uint(x);
    return (u16)((u + 0x7FFFu + ((u >> 16) & 1u)) >> 16);
}
__device__ __forceinline__ void gload16(const u16* src, u16* dst) {
    __builtin_amdgcn_global_load_lds(
        (const __attribute__((address_space(1))) void*)src,
        (__attribute__((address_space(3))) void*)dst, 16, 0, 0);
}

// ---- K0: normalize rows, split bf16 hi/lo, write plane-major layout
// dst[plane][row][8]; planes 0..31 = hi k-octets, 32..63 = lo. (r7/r11-verified)
__global__ void k_prep(const float* __restrict__ src, u16* __restrict__ dst,
                       size_t planeStride) {
    __shared__ u16 L[64][264];
    const int t = threadIdx.x, w = t >> 6, lane = t & 63;
    const int rbase = blockIdx.x * 64;

    ushort4 lo_save[16];

    #pragma unroll
    for (int i = 0; i < 16; ++i) {
        int row = rbase + w * 16 + i;
        float4 v = *(const float4*)(src + (size_t)row * DIM + 4 * lane);
        float ss = v.x * v.x + v.y * v.y + v.z * v.z + v.w * v.w;
        #pragma unroll
        for (int o = 32; o > 0; o >>= 1) ss += __shfl_down(ss, o, 64);
        ss = __shfl(ss, 0, 64);
        float inv = 1.0f / fmaxf(sqrtf(ss), 1e-12f);
        float e[4] = {v.x * inv, v.y * inv, v.z * inv, v.w * inv};
        u16 hh[4], ll[4];
        #pragma unroll
        for (int q = 0; q < 4; ++q) {
            hh[q] = bf_rne(e[q]);
            float hf = __uint_as_float(((u32)hh[q]) << 16);
            ll[q] = bf_rne(e[q] - hf);
        }
        *(ushort4*)&L[w * 16 + i][4 * lane] = make_ushort4(hh[0], hh[1], hh[2], hh[3]);
        lo_save[i] = make_ushort4(ll[0], ll[1], ll[2], ll[3]);
    }
    __syncthreads();
    #pragma unroll
    for (int q = 0; q < 8; ++q) {
        int c = q * 256 + t;
        int kb = c >> 6, r = c & 63;
        short8 val = *(const short8*)&L[r][kb * 8];
        *(short8*)(dst + (size_t)kb * planeStride + (size_t)(rbase + r) * 8) = val;
    }
    __syncthreads();
    #pragma unroll
    for (int i = 0; i < 16; ++i)
        *(ushort4*)&L[w * 16 + i][4 * lane] = lo_save[i];
    __syncthreads();
    #pragma unroll
    for (int q = 0; q < 8; ++q) {
        int c = q * 256 + t;
        int kb = c >> 6, r = c & 63;
        short8 val = *(const short8*)&L[r][kb * 8];
        *(short8*)(dst + (size_t)(32 + kb) * planeStride + (size_t)(rbase + r) * 8) = val;
    }
}

// ---- K2: persistent-panel MFMA GEMM. Grid = 1024 blocks (4/CU, no tail).
// Each block owns one 128-row panel, loops 16 col-tiles x 16 chunks as one
// continuous pipeline (u = 0..255, dbuf never drains). Per-tile chunk
// schedule + FP order identical to r17. Epilogue uses dedicated LDS scratch
// (no buffer collision with staged-ahead chunk). 36 KB LDS -> 4 blocks/CU.
__launch_bounds__(256, 4)
__global__ void k_mfma(const u16* __restrict__ zpk, const u16* __restrict__ epk,
                       u64* __restrict__ rowmax, u64* __restrict__ colmax) {
    __shared__ __align__(16) u16 lds[SCR + 2048];   // buf0 | buf1 | 4KB scratch
    const int t = threadIdx.x;
    const int lane = t & 63, l31 = lane & 31, lhi = lane >> 5;
    const int w = t >> 6, wr = w >> 1, wc = w & 1;

    // bijective XCD swizzle (nwg=1024, 128 panels per XCD)
    const int panel = (blockIdx.x & 7) * 128 + (blockIdx.x >> 3);
    const int brow = panel * 128;

    const size_t ZPS = (size_t)NROWS * 8;   // z plane stride (u16)
    const size_t EPS = (size_t)KCB * 8;     // e plane stride (u16)

    f32x16 acc[2][2];
    #pragma unroll
    for (int i = 0; i < 2; ++i)
        #pragma unroll
        for (int j = 0; j < 2; ++j)
            #pragma unroll
            for (int r = 0; r < 16; ++r) acc[i][j][r] = 0.f;

    // ---- hoisted staging sources ----
    const int ph = t >> 7;          // which of the two planes this thread loads
    const int rr = t & 127;         // row within tile
    const u16* sAh = zpk + (size_t)ph * ZPS + (size_t)(brow + rr) * 8;          // A hi
    const u16* sAl = zpk + (size_t)(32 + ph) * ZPS + (size_t)(brow + rr) * 8;   // A lo
    const u16* sBh = epk + (size_t)ph * EPS + (size_t)rr * 8;                   // + bcol*8
    const u16* sBl = epk + (size_t)(32 + ph) * EPS + (size_t)rr * 8;
    const int dA0 = t * 8, dA1 = (256 + t) * 8;
    const int dB0 = 4096 + t * 8, dB1 = 4096 + (256 + t) * 8;

    // ---- precomputed fragment LDS offsets (within a buffer) ----
    int aH[2], aL[2], bH[2], bL[2];
    #pragma unroll
    for (int i = 0; i < 2; ++i) {
        int r = wr * 64 + i * 32 + l31;
        aH[i] = (lhi * 128 + r) * 8;
        aL[i] = ((2 + lhi) * 128 + r) * 8;
    }
    #pragma unroll
    for (int j = 0; j < 2; ++j) {
        int r = wc * 64 + j * 32 + l31;
        bH[j] = 4096 + (lhi * 128 + r) * 8;
        bL[j] = 4096 + ((2 + lhi) * 128 + r) * 8;
    }

    // stage linearized chunk u into buffer b: tile ct = u>>4, k-chunk c = u&15
    auto stage = [&](int b, int u) {
        const int c = u & 15;
        const size_t bo = (size_t)((u >> 4) * 128) * 8;   // bcol offset (u16)
        const size_t oz = (size_t)(2 * c) * ZPS;
        const size_t oe = (size_t)(2 * c) * EPS;
        gload16(sAh + oz, &lds[b * BUF + dA0]);
        gload16(sAl + oz, &lds[b * BUF + dA1]);
        gload16(sBh + bo + oe, &lds[b * BUF + dB0]);
        gload16(sBl + bo + oe, &lds[b * BUF + dB1]);
    };

    float2* colred = (float2*)&lds[SCR];          // [2 wr][128 cols], 2 KB
    float2* rowred = (float2*)&lds[SCR + 1024];   // [2 wc][128 rows], 2 KB

    stage(0, 0);
    asm volatile("s_waitcnt vmcnt(0)" ::: "memory");
    __builtin_amdgcn_s_barrier();

    #pragma unroll 2
    for (int u = 0; u < 256; ++u) {
        const int b = u & 1;
        if (u + 1 < 256) stage(b ^ 1, u + 1);   // prefetch overlaps comp below

        // ---- comp(b): identical frag loads + MFMA order to r17 ----
        short8 zh[2], zl[2], eh[2], el[2];
        #pragma unroll
        for (int i = 0; i < 2; ++i) {
            zh[i] = *(const short8*)&lds[b * BUF + aH[i]];
            zl[i] = *(const short8*)&lds[b * BUF + aL[i]];
        }
        #pragma unroll
        for (int j = 0; j < 2; ++j) {
            eh[j] = *(const short8*)&lds[b * BUF + bH[j]];
            el[j] = *(const short8*)&lds[b * BUF + bL[j]];
        }

        __builtin_amdgcn_s_setprio(1);
        #pragma unroll
        for (int i = 0; i < 2; ++i)
            #pragma unroll
            for (int j = 0; j < 2; ++j)
                acc[i][j] = __builtin_amdgcn_mfma_f32_32x32x16_bf16(zh[i], eh[j], acc[i][j], 0, 0, 0);
        #pragma unroll
        for (int i = 0; i < 2; ++i)
            #pragma unroll
            for (int j = 0; j < 2; ++j)
                acc[i][j] = __builtin_amdgcn_mfma_f32_32x32x16_bf16(zl[i], eh[j], acc[i][j], 0, 0, 0);
        #pragma unroll
        for (int i = 0; i < 2; ++i)
            #pragma unroll
            for (int j = 0; j < 2; ++j)
                acc[i][j] = __builtin_amdgcn_mfma_f32_32x32x16_bf16(zh[i], el[j], acc[i][j], 0, 0, 0);
        __builtin_amdgcn_s_setprio(0);

        if (u + 1 < 256) { asm volatile("s_waitcnt vmcnt(0)" ::: "memory"); }
        __builtin_amdgcn_s_barrier();          // next chunk staged AND buf b free

        // ---- per-col-tile epilogue (every 16 chunks); scratch region only ----
        if ((u & 15) == 15) {
            const int bcol = (u >> 4) * 128;

            #pragma unroll
            for (int j = 0; j < 2; ++j) {
                float bv = -3.4e38f; int brw = 0x7FFFFFFF;
                #pragma unroll
                for (int i = 0; i < 2; ++i)
                    #pragma unroll
                    for (int r = 0; r < 16; ++r) {
                        float v = acc[i][j][r];
                        int rg = brow + wr * 64 + i * 32 + (r & 3) + 8 * (r >> 2) + 4 * lhi;
                        if (v > bv || (v == bv && rg < brw)) { bv = v; brw = rg; }
                    }
                float ov = __shfl_xor(bv, 32); int orw = __shfl_xor(brw, 32);
                if (ov > bv || (ov == bv && orw < brw)) { bv = ov; brw = orw; }
                if (lane < 32) colred[wr * 128 + wc * 64 + j * 32 + l31] = make_float2(bv, __int_as_float(brw));
            }

            #pragma unroll
            for (int i = 0; i < 2; ++i) {
                #pragma unroll
                for (int r = 0; r < 16; ++r) {
                    float bv = -3.4e38f; int bc = 0x7FFFFFFF;
                    #pragma unroll
                    for (int j = 0; j < 2; ++j) {
                        float v = acc[i][j][r];
                        int cg = bcol + wc * 64 + j * 32 + l31;
                        if (v > bv || (v == bv && cg < bc)) { bv = v; bc = cg; }
                    }
                    #pragma unroll
                    for (int m = 16; m >= 1; m >>= 1) {
                        float ov = __shfl_xor(bv, m);
                        int oc = __shfl_xor(bc, m);
                        if (ov > bv || (ov == bv && oc < bc)) { bv = ov; bc = oc; }
                    }
                    if (l31 == 0) {
                        int rloc = wr * 64 + i * 32 + (r & 3) + 8 * (r >> 2) + 4 * lhi;
                        rowred[wc * 128 + rloc] = make_float2(bv, __int_as_float(bc));
                    }
                }
            }
            __syncthreads();

            if (t < 128) {
                float2 e0 = colred[t], e1 = colred[128 + t];
                float bv = e0.x; int brw = __float_as_int(e0.y);
                if (e1.x > bv || (e1.x == bv && __float_as_int(e1.y) < brw)) { bv = e1.x; brw = __float_as_int(e1.y); }
                atomicMax(colmax + bcol + t, ((u64)fkey(bv) << 32) | (u64)(~(u32)brw));

                float2 r0 = rowred[t], r1 = rowred[128 + t];
                float rv = r0.x; int rc = __float_as_int(r0.y);
                if (r1.x > rv || (r1.x == rv && __float_as_int(r1.y) < rc)) { rv = r1.x; rc = __float_as_int(r1.y); }
                atomicMax(rowmax + brow + t, ((u64)fkey(rv) << 32) | (u64)(~(u32)rc));
            }

            // reset accumulators for the next col-tile
            #pragma unroll
            for (int i = 0; i < 2; ++i)
                #pragma unroll
                for (int j = 0; j < 2; ++j)
                    #pragma unroll
                    for (int r = 0; r < 16; ++r) acc[i][j][r] = 0.f;
        }
    }
}

// ---- K3: gather z_q, write out0, loss partials, histogram ----
__global__ void k_gather(const float* __restrict__ z, const float* __restrict__ emb,
                         const u64* __restrict__ rowmax, float* __restrict__ zq_out,
                         int* __restrict__ counts, float* __restrict__ partials) {
    __shared__ float red[256];
    int t = threadIdx.x;
    int lane = t & 63, w = t >> 6;
    int base = blockIdx.x * 64;
    float acc = 0.f;
    for (int r = 0; r < 16; ++r) {
        int row = base + w * 16 + r;
        int ix = (int)(~(u32)(rowmax[row] & 0xFFFFFFFFull));
        float4 e  = *(const float4*)(emb + (size_t)ix * DIM + 4 * lane);
        float4 zv = *(const float4*)(z + (size_t)row * DIM + 4 * lane);
        float4 o;
        o.x = zv.x + (e.x - zv.x); o.y = zv.y + (e.y - zv.y);
        o.z = zv.z + (e.z - zv.z); o.w = zv.w + (e.w - zv.w);
        *(float4*)(zq_out + (size_t)row * DIM + 4 * lane) = o;
        float dx = e.x - zv.x, dy = e.y - zv.y, dz = e.z - zv.z, dw = e.w - zv.w;
        acc += dx * dx + dy * dy + dz * dz + dw * dw;
        if (lane == 0) atomicAdd(counts + ix, 1);
    }
    red[t] = acc;
    __syncthreads();
    #pragma unroll
    for (int o = 128; o > 0; o >>= 1) { if (t < o) red[t] += red[t + o]; __syncthreads(); }
    if (t == 0) partials[blockIdx.x] = red[0];
}

// ---- K4: final loss reduce ----
__global__ void k_loss(const float* __restrict__ partials, float* __restrict__ out_loss) {
    __shared__ float red[256];
    int t = threadIdx.x;
    float a = 0.f;
    for (int i = t; i < 2048; i += 256) a += partials[i];
    red[t] = a;
    __syncthreads();
    #pragma unroll
    for (int o = 128; o > 0; o >>= 1) { if (t < o) red[t] += red[t + o]; __syncthreads(); }
    if (t == 0) out_loss[0] = 1.25f * (red[0] / 33554432.0f);
}

// ---- K5: finalize new_embedding + new_embed_prob ----
__global__ void k_final(const float* __restrict__ z, const float* __restrict__ emb,
                        const float* __restrict__ eprob, const int* __restrict__ counts,
                        const u64* __restrict__ colmax,
                        float* __restrict__ out_emb, float* __restrict__ out_prob) {
    int k = blockIdx.x, lane = threadIdx.x;
    int r = (int)(~(u32)(colmax[k] & 0xFFFFFFFFull));
    float avg = (float)counts[k] * (1.0f / (float)NROWS);
    float nep = eprob[k] * 0.99f + avg * 0.01f;
    float reinit = expf(-(((nep * 2048.0f) * 10.0f) / 0.01f) - 0.001f);
    float4 ev = *(const float4*)(emb + (size_t)k * DIM + 4 * lane);
    float4 zv = *(const float4*)(z + (size_t)r * DIM + 4 * lane);
    float4 o;
    o.x = ev.x * (1.f - reinit) + zv.x * reinit;
    o.y = ev.y * (1.f - reinit) + zv.y * reinit;
    o.z = ev.z * (1.f - reinit) + zv.z * reinit;
    o.w = ev.w * (1.f - reinit) + zv.w * reinit;
    *(float4*)(out_emb + (size_t)k * DIM + 4 * lane) = o;
    if (lane == 0) out_prob[k] = nep;
}

extern "C" void kernel_launch(void* const* d_in, const int* in_sizes, int n_in,
                              void* d_out, int out_size, void* d_ws, size_t ws_size,
                              hipStream_t stream) {
    const float* z   = (const float*)d_in[0];
    const float* emb = (const float*)d_in[1];
    const float* epr = (const float*)d_in[2];

    float* out      = (float*)d_out;
    float* out_zq   = out;
    float* out_loss = out + (size_t)NROWS * DIM;
    float* out_emb  = out_loss + 1;
    float* out_prob = out_emb + (size_t)KCB * DIM;

    // z_pk aliases the zq region of d_out; overwritten by k_gather afterwards.
    u16* zpk = (u16*)d_out;

    char* ws = (char*)d_ws;
    u16*   epk    = (u16*)  (ws + 0);          // 2 MB
    u64*   rowmax = (u64*)  (ws + 2097152);    // 1 MB
    u64*   colmax = (u64*)  (ws + 3145728);    // 16 KB
    int*   counts = (int*)  (ws + 3162112);    // 8 KB
    float* parts  = (float*)(ws + 3170304);    // 8 KB

    hipMemsetAsync(rowmax, 0, 1048576 + 16384 + 8192, stream);

    k_prep<<<NROWS / 64, 256, 0, stream>>>(z, zpk, (size_t)NROWS * 8);
    k_prep<<<KCB / 64, 256, 0, stream>>>(emb, epk, (size_t)KCB * 8);
    k_mfma<<<NROWS / 128, 256, 0, stream>>>(zpk, epk, rowmax, colmax);
    k_gather<<<NROWS / 64, 256, 0, stream>>>(z, emb, rowmax, out_zq, counts, parts);
    k_loss<<<1, 256, 0, stream>>>(parts, out_loss);
    k_final<<<KCB, 64, 0, stream>>>(z, emb, epr, counts, colmax, out_emb, out_prob);
}

// Round 19
// 541.221 us; speedup vs baseline: 1.5094x; 1.5094x over previous
//
#include <hip/hip_runtime.h>

#define NROWS 131072
#define KCB   2048
#define DIM   256

typedef unsigned int u32;
typedef unsigned long long u64;
typedef unsigned short u16;
typedef __attribute__((ext_vector_type(8))) short short8;
typedef __attribute__((ext_vector_type(16))) float f32x16;

__device__ __forceinline__ u32 fkey(float f) {
    u32 b = __float_as_uint(f);
    return (b & 0x80000000u) ? ~b : (b | 0x80000000u);
}
__device__ __forceinline__ u16 bf_rne(float x) {
    u32 u = __float_as_uint(x);
    return (u16)((u + 0x7FFFu + ((u >> 16) & 1u)) >> 16);
}
__device__ __forceinline__ void gload16(const u16* src, u16* dst) {
    __builtin_amdgcn_global_load_lds(
        (const __attribute__((address_space(1))) void*)src,
        (__attribute__((address_space(3))) void*)dst, 16, 0, 0);
}

// ---- K0: normalize rows, round to bf16 (single precision), write plane-major
// layout dst[plane][row][8], planes 0..31 (k-octets).
__global__ void k_prep(const float* __restrict__ src, u16* __restrict__ dst,
                       size_t planeStride) {
    __shared__ u16 L[64][264];
    const int t = threadIdx.x, w = t >> 6, lane = t & 63;
    const int rbase = blockIdx.x * 64;

    #pragma unroll
    for (int i = 0; i < 16; ++i) {
        int row = rbase + w * 16 + i;
        float4 v = *(const float4*)(src + (size_t)row * DIM + 4 * lane);
        float ss = v.x * v.x + v.y * v.y + v.z * v.z + v.w * v.w;
        #pragma unroll
        for (int o = 32; o > 0; o >>= 1) ss += __shfl_down(ss, o, 64);
        ss = __shfl(ss, 0, 64);
        float inv = 1.0f / fmaxf(sqrtf(ss), 1e-12f);
        u16 hh[4] = {bf_rne(v.x * inv), bf_rne(v.y * inv),
                     bf_rne(v.z * inv), bf_rne(v.w * inv)};
        *(ushort4*)&L[w * 16 + i][4 * lane] = make_ushort4(hh[0], hh[1], hh[2], hh[3]);
    }
    __syncthreads();
    #pragma unroll
    for (int q = 0; q < 8; ++q) {
        int c = q * 256 + t;
        int kb = c >> 6, r = c & 63;
        short8 val = *(const short8*)&L[r][kb * 8];
        *(short8*)(dst + (size_t)kb * planeStride + (size_t)(rbase + r) * 8) = val;
    }
}

// ---- K2: MFMA GEMM, single-pass bf16. 128x128 tile, 4 waves (2x2),
// wave-tile 64x64, BK=32 (4 octet-planes/chunk), 8 chunks. Per chunk:
// 4 gloads + 8 conflict-free ds_read_b128 + 8 MFMA + 1 vmcnt(0) + 1 barrier.
// (r17 structure with the lo-planes removed: 3x less MFMA, 2x less staging.)
__launch_bounds__(256, 4)
__global__ void k_mfma(const u16* __restrict__ zpk, const u16* __restrict__ epk,
                       u64* __restrict__ rowmax, u64* __restrict__ colmax) {
    // per buffer (u16 idx): A [0,4096) = [4 planes][128 rows][8]; B [4096,8192)
    // plane p of chunk c = global k-octet 4c+p.
    __shared__ __align__(16) u16 lds[2][8192];
    const int t = threadIdx.x;
    const int lane = t & 63, l31 = lane & 31, lhi = lane >> 5;
    const int w = t >> 6, wr = w >> 1, wc = w & 1;

    // bijective XCD swizzle (nwg=16384, 2048/XCD)
    const int swz = (blockIdx.x & 7) * 2048 + (blockIdx.x >> 3);
    const int brow = (swz >> 4) * 128;
    const int bcol = (swz & 15) * 128;

    const size_t ZPS = (size_t)NROWS * 8;   // z plane stride (u16)
    const size_t EPS = (size_t)KCB * 8;     // e plane stride (u16)

    f32x16 acc[2][2];
    #pragma unroll
    for (int i = 0; i < 2; ++i)
        #pragma unroll
        for (int j = 0; j < 2; ++j)
            #pragma unroll
            for (int r = 0; r < 16; ++r) acc[i][j][r] = 0.f;

    // ---- hoisted staging sources (chunk 0); chunk c adds 4c*planeStride ----
    const int ph = t >> 7;          // plane sub-index 0..1 for this thread
    const int rr = t & 127;         // row within tile
    const u16* sA0 = zpk + (size_t)ph * ZPS + (size_t)(brow + rr) * 8;         // planes 0,1
    const u16* sA1 = zpk + (size_t)(2 + ph) * ZPS + (size_t)(brow + rr) * 8;   // planes 2,3
    const u16* sB0 = epk + (size_t)ph * EPS + (size_t)(bcol + rr) * 8;
    const u16* sB1 = epk + (size_t)(2 + ph) * EPS + (size_t)(bcol + rr) * 8;
    const int dA0 = t * 8, dA1 = (256 + t) * 8;
    const int dB0 = 4096 + t * 8, dB1 = 4096 + (256 + t) * 8;

    // ---- precomputed fragment LDS offsets (u16 idx) ----
    int aK0[2], aK1[2], bK0[2], bK1[2];
    #pragma unroll
    for (int i = 0; i < 2; ++i) {
        int r = wr * 64 + i * 32 + l31;
        aK0[i] = (lhi * 128 + r) * 8;            // k-slice 0: planes lhi
        aK1[i] = ((2 + lhi) * 128 + r) * 8;      // k-slice 1: planes 2+lhi
    }
    #pragma unroll
    for (int j = 0; j < 2; ++j) {
        int r = wc * 64 + j * 32 + l31;
        bK0[j] = 4096 + (lhi * 128 + r) * 8;
        bK1[j] = 4096 + ((2 + lhi) * 128 + r) * 8;
    }

    auto stage = [&](int b, int c) {
        const size_t oz = (size_t)(4 * c) * ZPS;
        const size_t oe = (size_t)(4 * c) * EPS;
        gload16(sA0 + oz, &lds[b][dA0]);
        gload16(sA1 + oz, &lds[b][dA1]);
        gload16(sB0 + oe, &lds[b][dB0]);
        gload16(sB1 + oe, &lds[b][dB1]);
    };

    stage(0, 0);
    asm volatile("s_waitcnt vmcnt(0)" ::: "memory");
    __builtin_amdgcn_s_barrier();

    #pragma unroll
    for (int c = 0; c < 8; ++c) {
        const int b = c & 1;
        if (c + 1 < 8) stage(b ^ 1, c + 1);    // prefetch overlaps comp below

        short8 z0[2], z1[2], e0[2], e1[2];
        #pragma unroll
        for (int i = 0; i < 2; ++i) {
            z0[i] = *(const short8*)&lds[b][aK0[i]];
            z1[i] = *(const short8*)&lds[b][aK1[i]];
        }
        #pragma unroll
        for (int j = 0; j < 2; ++j) {
            e0[j] = *(const short8*)&lds[b][bK0[j]];
            e1[j] = *(const short8*)&lds[b][bK1[j]];
        }

        __builtin_amdgcn_s_setprio(1);
        #pragma unroll
        for (int i = 0; i < 2; ++i)
            #pragma unroll
            for (int j = 0; j < 2; ++j)
                acc[i][j] = __builtin_amdgcn_mfma_f32_32x32x16_bf16(z0[i], e0[j], acc[i][j], 0, 0, 0);
        #pragma unroll
        for (int i = 0; i < 2; ++i)
            #pragma unroll
            for (int j = 0; j < 2; ++j)
                acc[i][j] = __builtin_amdgcn_mfma_f32_32x32x16_bf16(z1[i], e1[j], acc[i][j], 0, 0, 0);
        __builtin_amdgcn_s_setprio(0);

        if (c + 1 < 8) { asm volatile("s_waitcnt vmcnt(0)" ::: "memory"); }
        __builtin_amdgcn_s_barrier();
    }

    // ---- epilogue: argmax reductions (r12/r17-verified 2x2/64x64 semantics) ----
    float2* colred = (float2*)&lds[0][0];      // [2 wr][128 cols]
    float2* rowred = (float2*)&lds[0][1024];   // [2 wc][128 rows]

    #pragma unroll
    for (int j = 0; j < 2; ++j) {
        float bv = -3.4e38f; int brw = 0x7FFFFFFF;
        #pragma unroll
        for (int i = 0; i < 2; ++i)
            #pragma unroll
            for (int r = 0; r < 16; ++r) {
                float v = acc[i][j][r];
                int rg = brow + wr * 64 + i * 32 + (r & 3) + 8 * (r >> 2) + 4 * lhi;
                if (v > bv || (v == bv && rg < brw)) { bv = v; brw = rg; }
            }
        float ov = __shfl_xor(bv, 32); int orw = __shfl_xor(brw, 32);
        if (ov > bv || (ov == bv && orw < brw)) { bv = ov; brw = orw; }
        if (lane < 32) colred[wr * 128 + wc * 64 + j * 32 + l31] = make_float2(bv, __int_as_float(brw));
    }

    #pragma unroll
    for (int i = 0; i < 2; ++i) {
        #pragma unroll
        for (int r = 0; r < 16; ++r) {
            float bv = -3.4e38f; int bc = 0x7FFFFFFF;
            #pragma unroll
            for (int j = 0; j < 2; ++j) {
                float v = acc[i][j][r];
                int cg = bcol + wc * 64 + j * 32 + l31;
                if (v > bv || (v == bv && cg < bc)) { bv = v; bc = cg; }
            }
            #pragma unroll
            for (int m = 16; m >= 1; m >>= 1) {
                float ov = __shfl_xor(bv, m);
                int oc = __shfl_xor(bc, m);
                if (ov > bv || (ov == bv && oc < bc)) { bv = ov; bc = oc; }
            }
            if (l31 == 0) {
                int rloc = wr * 64 + i * 32 + (r & 3) + 8 * (r >> 2) + 4 * lhi;
                rowred[wc * 128 + rloc] = make_float2(bv, __int_as_float(bc));
            }
        }
    }
    __syncthreads();

    if (t < 128) {
        float2 e0_ = colred[t], e1_ = colred[128 + t];
        float bv = e0_.x; int brw = __float_as_int(e0_.y);
        if (e1_.x > bv || (e1_.x == bv && __float_as_int(e1_.y) < brw)) { bv = e1_.x; brw = __float_as_int(e1_.y); }
        atomicMax(colmax + bcol + t, ((u64)fkey(bv) << 32) | (u64)(~(u32)brw));

        float2 r0 = rowred[t], r1 = rowred[128 + t];
        float rv = r0.x; int rc = __float_as_int(r0.y);
        if (r1.x > rv || (r1.x == rv && __float_as_int(r1.y) < rc)) { rv = r1.x; rc = __float_as_int(r1.y); }
        atomicMax(rowmax + brow + t, ((u64)fkey(rv) << 32) | (u64)(~(u32)rc));
    }
}

// ---- K3: gather z_q, write out0, loss partials, histogram ----
__global__ void k_gather(const float* __restrict__ z, const float* __restrict__ emb,
                         const u64* __restrict__ rowmax, float* __restrict__ zq_out,
                         int* __restrict__ counts, float* __restrict__ partials) {
    __shared__ float red[256];
    int t = threadIdx.x;
    int lane = t & 63, w = t >> 6;
    int base = blockIdx.x * 64;
    float acc = 0.f;
    for (int r = 0; r < 16; ++r) {
        int row = base + w * 16 + r;
        int ix = (int)(~(u32)(rowmax[row] & 0xFFFFFFFFull));
        float4 e  = *(const float4*)(emb + (size_t)ix * DIM + 4 * lane);
        float4 zv = *(const float4*)(z + (size_t)row * DIM + 4 * lane);
        float4 o;
        o.x = zv.x + (e.x - zv.x); o.y = zv.y + (e.y - zv.y);
        o.z = zv.z + (e.z - zv.z); o.w = zv.w + (e.w - zv.w);
        *(float4*)(zq_out + (size_t)row * DIM + 4 * lane) = o;
        float dx = e.x - zv.x, dy = e.y - zv.y, dz = e.z - zv.z, dw = e.w - zv.w;
        acc += dx * dx + dy * dy + dz * dz + dw * dw;
        if (lane == 0) atomicAdd(counts + ix, 1);
    }
    red[t] = acc;
    __syncthreads();
    #pragma unroll
    for (int o = 128; o > 0; o >>= 1) { if (t < o) red[t] += red[t + o]; __syncthreads(); }
    if (t == 0) partials[blockIdx.x] = red[0];
}

// ---- K4: final loss reduce ----
__global__ void k_loss(const float* __restrict__ partials, float* __restrict__ out_loss) {
    __shared__ float red[256];
    int t = threadIdx.x;
    float a = 0.f;
    for (int i = t; i < 2048; i += 256) a += partials[i];
    red[t] = a;
    __syncthreads();
    #pragma unroll
    for (int o = 128; o > 0; o >>= 1) { if (t < o) red[t] += red[t + o]; __syncthreads(); }
    if (t == 0) out_loss[0] = 1.25f * (red[0] / 33554432.0f);
}

// ---- K5: finalize new_embedding + new_embed_prob ----
__global__ void k_final(const float* __restrict__ z, const float* __restrict__ emb,
                        const float* __restrict__ eprob, const int* __restrict__ counts,
                        const u64* __restrict__ colmax,
                        float* __restrict__ out_emb, float* __restrict__ out_prob) {
    int k = blockIdx.x, lane = threadIdx.x;
    int r = (int)(~(u32)(colmax[k] & 0xFFFFFFFFull));
    float avg = (float)counts[k] * (1.0f / (float)NROWS);
    float nep = eprob[k] * 0.99f + avg * 0.01f;
    float reinit = expf(-(((nep * 2048.0f) * 10.0f) / 0.01f) - 0.001f);
    float4 ev = *(const float4*)(emb + (size_t)k * DIM + 4 * lane);
    float4 zv = *(const float4*)(z + (size_t)r * DIM + 4 * lane);
    float4 o;
    o.x = ev.x * (1.f - reinit) + zv.x * reinit;
    o.y = ev.y * (1.f - reinit) + zv.y * reinit;
    o.z = ev.z * (1.f - reinit) + zv.z * reinit;
    o.w = ev.w * (1.f - reinit) + zv.w * reinit;
    *(float4*)(out_emb + (size_t)k * DIM + 4 * lane) = o;
    if (lane == 0) out_prob[k] = nep;
}

extern "C" void kernel_launch(void* const* d_in, const int* in_sizes, int n_in,
                              void* d_out, int out_size, void* d_ws, size_t ws_size,
                              hipStream_t stream) {
    const float* z   = (const float*)d_in[0];
    const float* emb = (const float*)d_in[1];
    const float* epr = (const float*)d_in[2];

    float* out      = (float*)d_out;
    float* out_zq   = out;
    float* out_loss = out + (size_t)NROWS * DIM;
    float* out_emb  = out_loss + 1;
    float* out_prob = out_emb + (size_t)KCB * DIM;

    // z_pk (32 planes x NROWS x 8 u16 = 64 MB) aliases the zq region of d_out;
    // overwritten by k_gather after k_mfma consumed it.
    u16* zpk = (u16*)d_out;

    char* ws = (char*)d_ws;
    u16*   epk    = (u16*)  (ws + 0);          // 1 MB used (32 planes)
    u64*   rowmax = (u64*)  (ws + 2097152);    // 1 MB
    u64*   colmax = (u64*)  (ws + 3145728);    // 16 KB
    int*   counts = (int*)  (ws + 3162112);    // 8 KB
    float* parts  = (float*)(ws + 3170304);    // 8 KB

    hipMemsetAsync(rowmax, 0, 1048576 + 16384 + 8192, stream);

    k_prep<<<NROWS / 64, 256, 0, stream>>>(z, zpk, (size_t)NROWS * 8);
    k_prep<<<KCB / 64, 256, 0, stream>>>(emb, epk, (size_t)KCB * 8);
    k_mfma<<<(NROWS / 128) * (KCB / 128), 256, 0, stream>>>(zpk, epk, rowmax, colmax);
    k_gather<<<NROWS / 64, 256, 0, stream>>>(z, emb, rowmax, out_zq, counts, parts);
    k_loss<<<1, 256, 0, stream>>>(parts, out_loss);
    k_final<<<KCB, 64, 0, stream>>>(z, emb, epr, counts, colmax, out_emb, out_prob);
}

// Round 20
// 466.971 us; speedup vs baseline: 1.7495x; 1.1590x over previous
//
#include <hip/hip_runtime.h>

#define NROWS 131072
#define KCB   2048
#define DIM   256

typedef unsigned int u32;
typedef unsigned long long u64;
typedef unsigned short u16;
typedef __attribute__((ext_vector_type(8))) short short8;
typedef __attribute__((ext_vector_type(16))) float f32x16;

__device__ __forceinline__ u32 fkey(float f) {
    u32 b = __float_as_uint(f);
    return (b & 0x80000000u) ? ~b : (b | 0x80000000u);
}
__device__ __forceinline__ u16 bf_rne(float x) {
    u32 u = __float_as_uint(x);
    return (u16)((u + 0x7FFFu + ((u >> 16) & 1u)) >> 16);
}
__device__ __forceinline__ void gload16(const u16* src, u16* dst) {
    __builtin_amdgcn_global_load_lds(
        (const __attribute__((address_space(1))) void*)src,
        (__attribute__((address_space(3))) void*)dst, 16, 0, 0);
}

// ---- K0: normalize rows, round to bf16, write plane-major layout
// dst[plane][row][8], planes 0..31 (k-octets). (r19-verified)
__global__ void k_prep(const float* __restrict__ src, u16* __restrict__ dst,
                       size_t planeStride) {
    __shared__ u16 L[64][264];
    const int t = threadIdx.x, w = t >> 6, lane = t & 63;
    const int rbase = blockIdx.x * 64;

    #pragma unroll
    for (int i = 0; i < 16; ++i) {
        int row = rbase + w * 16 + i;
        float4 v = *(const float4*)(src + (size_t)row * DIM + 4 * lane);
        float ss = v.x * v.x + v.y * v.y + v.z * v.z + v.w * v.w;
        #pragma unroll
        for (int o = 32; o > 0; o >>= 1) ss += __shfl_down(ss, o, 64);
        ss = __shfl(ss, 0, 64);
        float inv = 1.0f / fmaxf(sqrtf(ss), 1e-12f);
        u16 hh[4] = {bf_rne(v.x * inv), bf_rne(v.y * inv),
                     bf_rne(v.z * inv), bf_rne(v.w * inv)};
        *(ushort4*)&L[w * 16 + i][4 * lane] = make_ushort4(hh[0], hh[1], hh[2], hh[3]);
    }
    __syncthreads();
    #pragma unroll
    for (int q = 0; q < 8; ++q) {
        int c = q * 256 + t;
        int kb = c >> 6, r = c & 63;
        short8 val = *(const short8*)&L[r][kb * 8];
        *(short8*)(dst + (size_t)kb * planeStride + (size_t)(rbase + r) * 8) = val;
    }
}

// ---- K2: MFMA GEMM, single-pass bf16, 128x128 tile, 4 waves (2x2),
// wave-tile 64x64, BK=32, 8 chunks. r12-style 2-deep counted-vmcnt pipeline:
// stage(b,c+2) after comp, vmcnt(4) waits only for chunk c+1 (issued a full
// chunk earlier -> latency covered). FP math identical to r19.
__launch_bounds__(256, 4)
__global__ void k_mfma(const u16* __restrict__ zpk, const u16* __restrict__ epk,
                       u64* __restrict__ rowmax, u64* __restrict__ colmax) {
    // per buffer (u16 idx): A [0,4096) = [4 planes][128 rows][8]; B [4096,8192)
    __shared__ __align__(16) u16 lds[2][8192];
    const int t = threadIdx.x;
    const int lane = t & 63, l31 = lane & 31, lhi = lane >> 5;
    const int w = t >> 6, wr = w >> 1, wc = w & 1;

    // bijective XCD swizzle (nwg=16384, 2048/XCD)
    const int swz = (blockIdx.x & 7) * 2048 + (blockIdx.x >> 3);
    const int brow = (swz >> 4) * 128;
    const int bcol = (swz & 15) * 128;

    const size_t ZPS = (size_t)NROWS * 8;   // z plane stride (u16)
    const size_t EPS = (size_t)KCB * 8;     // e plane stride (u16)

    f32x16 acc[2][2];
    #pragma unroll
    for (int i = 0; i < 2; ++i)
        #pragma unroll
        for (int j = 0; j < 2; ++j)
            #pragma unroll
            for (int r = 0; r < 16; ++r) acc[i][j][r] = 0.f;

    // ---- hoisted staging sources (chunk 0); chunk c adds 4c*planeStride ----
    const int ph = t >> 7;          // plane sub-index 0..1 for this thread
    const int rr = t & 127;         // row within tile
    const u16* sA0 = zpk + (size_t)ph * ZPS + (size_t)(brow + rr) * 8;         // planes 0,1
    const u16* sA1 = zpk + (size_t)(2 + ph) * ZPS + (size_t)(brow + rr) * 8;   // planes 2,3
    const u16* sB0 = epk + (size_t)ph * EPS + (size_t)(bcol + rr) * 8;
    const u16* sB1 = epk + (size_t)(2 + ph) * EPS + (size_t)(bcol + rr) * 8;
    const int dA0 = t * 8, dA1 = (256 + t) * 8;
    const int dB0 = 4096 + t * 8, dB1 = 4096 + (256 + t) * 8;

    // ---- precomputed fragment LDS offsets (u16 idx) ----
    int aK0[2], aK1[2], bK0[2], bK1[2];
    #pragma unroll
    for (int i = 0; i < 2; ++i) {
        int r = wr * 64 + i * 32 + l31;
        aK0[i] = (lhi * 128 + r) * 8;
        aK1[i] = ((2 + lhi) * 128 + r) * 8;
    }
    #pragma unroll
    for (int j = 0; j < 2; ++j) {
        int r = wc * 64 + j * 32 + l31;
        bK0[j] = 4096 + (lhi * 128 + r) * 8;
        bK1[j] = 4096 + ((2 + lhi) * 128 + r) * 8;
    }

    auto stage = [&](int b, int c) {
        const size_t oz = (size_t)(4 * c) * ZPS;
        const size_t oe = (size_t)(4 * c) * EPS;
        gload16(sA0 + oz, &lds[b][dA0]);
        gload16(sA1 + oz, &lds[b][dA1]);
        gload16(sB0 + oe, &lds[b][dB0]);
        gload16(sB1 + oe, &lds[b][dB1]);
    };

    // prologue: 2-deep prefetch
    stage(0, 0);
    stage(1, 1);
    asm volatile("s_waitcnt vmcnt(4)" ::: "memory");   // chunk 0 landed
    __builtin_amdgcn_s_barrier();

    #pragma unroll
    for (int c = 0; c < 8; ++c) {
        const int b = c & 1;

        short8 z0[2], z1[2], e0[2], e1[2];
        #pragma unroll
        for (int i = 0; i < 2; ++i) {
            z0[i] = *(const short8*)&lds[b][aK0[i]];
            z1[i] = *(const short8*)&lds[b][aK1[i]];
        }
        #pragma unroll
        for (int j = 0; j < 2; ++j) {
            e0[j] = *(const short8*)&lds[b][bK0[j]];
            e1[j] = *(const short8*)&lds[b][bK1[j]];
        }

        __builtin_amdgcn_s_setprio(1);
        #pragma unroll
        for (int i = 0; i < 2; ++i)
            #pragma unroll
            for (int j = 0; j < 2; ++j)
                acc[i][j] = __builtin_amdgcn_mfma_f32_32x32x16_bf16(z0[i], e0[j], acc[i][j], 0, 0, 0);
        #pragma unroll
        for (int i = 0; i < 2; ++i)
            #pragma unroll
            for (int j = 0; j < 2; ++j)
                acc[i][j] = __builtin_amdgcn_mfma_f32_32x32x16_bf16(z1[i], e1[j], acc[i][j], 0, 0, 0);
        __builtin_amdgcn_s_setprio(0);

        __builtin_amdgcn_s_barrier();                  // all waves done reading buf b
        if (c + 2 < 8) {
            stage(b, c + 2);
            asm volatile("s_waitcnt vmcnt(4)" ::: "memory");   // chunk c+1 landed
        } else if (c == 6) {
            asm volatile("s_waitcnt vmcnt(0)" ::: "memory");   // chunk 7 landed
        }
        __builtin_amdgcn_s_barrier();
    }

    // ---- epilogue: argmax reductions (tie-break: val desc, index asc) ----
    float2* colred = (float2*)&lds[0][0];      // [2 wr][128 cols]  (2 KB)
    float2* rowred = (float2*)&lds[0][1024];   // [2 wc][128 rows][4] (8 KB)

    // col argmax: unchanged from r19
    #pragma unroll
    for (int j = 0; j < 2; ++j) {
        float bv = -3.4e38f; int brw = 0x7FFFFFFF;
        #pragma unroll
        for (int i = 0; i < 2; ++i)
            #pragma unroll
            for (int r = 0; r < 16; ++r) {
                float v = acc[i][j][r];
                int rg = brow + wr * 64 + i * 32 + (r & 3) + 8 * (r >> 2) + 4 * lhi;
                if (v > bv || (v == bv && rg < brw)) { bv = v; brw = rg; }
            }
        float ov = __shfl_xor(bv, 32); int orw = __shfl_xor(brw, 32);
        if (ov > bv || (ov == bv && orw < brw)) { bv = ov; brw = orw; }
        if (lane < 32) colred[wr * 128 + wc * 64 + j * 32 + l31] = make_float2(bv, __int_as_float(brw));
    }

    // row argmax: 3-step butterfly (m=16,8,4) -> 4 group candidates, LDS finish.
    // The (val>, val==&&idx<) merge is a commutative-associative semilattice, so
    // any reduce order yields (max val, min index) == numpy first-index argmax.
    #pragma unroll
    for (int i = 0; i < 2; ++i) {
        #pragma unroll
        for (int r = 0; r < 16; ++r) {
            float bv = -3.4e38f; int bc = 0x7FFFFFFF;
            #pragma unroll
            for (int j = 0; j < 2; ++j) {
                float v = acc[i][j][r];
                int cg = bcol + wc * 64 + j * 32 + l31;
                if (v > bv || (v == bv && cg < bc)) { bv = v; bc = cg; }
            }
            #pragma unroll
            for (int m = 16; m >= 4; m >>= 1) {
                float ov = __shfl_xor(bv, m);
                int oc = __shfl_xor(bc, m);
                if (ov > bv || (ov == bv && oc < bc)) { bv = ov; bc = oc; }
            }
            if (l31 < 4) {
                int grow = wr * 64 + i * 32 + (r & 3) + 8 * (r >> 2) + 4 * lhi;
                rowred[(wc * 128 + grow) * 4 + l31] = make_float2(bv, __int_as_float(bc));
            }
        }
    }
    __syncthreads();

    if (t < 128) {
        float2 e0_ = colred[t], e1_ = colred[128 + t];
        float bv = e0_.x; int brw = __float_as_int(e0_.y);
        if (e1_.x > bv || (e1_.x == bv && __float_as_int(e1_.y) < brw)) { bv = e1_.x; brw = __float_as_int(e1_.y); }
        atomicMax(colmax + bcol + t, ((u64)fkey(bv) << 32) | (u64)(~(u32)brw));

        float rv = -3.4e38f; int rc = 0x7FFFFFFF;
        #pragma unroll
        for (int q = 0; q < 8; ++q) {
            float2 e = rowred[((q >> 2) * 128 + t) * 4 + (q & 3)];
            float v = e.x; int c2 = __float_as_int(e.y);
            if (v > rv || (v == rv && c2 < rc)) { rv = v; rc = c2; }
        }
        atomicMax(rowmax + brow + t, ((u64)fkey(rv) << 32) | (u64)(~(u32)rc));
    }
}

// ---- K3: gather z_q, write out0, loss partials, histogram ----
__global__ void k_gather(const float* __restrict__ z, const float* __restrict__ emb,
                         const u64* __restrict__ rowmax, float* __restrict__ zq_out,
                         int* __restrict__ counts, float* __restrict__ partials) {
    __shared__ float red[256];
    int t = threadIdx.x;
    int lane = t & 63, w = t >> 6;
    int base = blockIdx.x * 64;
    float acc = 0.f;
    for (int r = 0; r < 16; ++r) {
        int row = base + w * 16 + r;
        int ix = (int)(~(u32)(rowmax[row] & 0xFFFFFFFFull));
        float4 e  = *(const float4*)(emb + (size_t)ix * DIM + 4 * lane);
        float4 zv = *(const float4*)(z + (size_t)row * DIM + 4 * lane);
        float4 o;
        o.x = zv.x + (e.x - zv.x); o.y = zv.y + (e.y - zv.y);
        o.z = zv.z + (e.z - zv.z); o.w = zv.w + (e.w - zv.w);
        *(float4*)(zq_out + (size_t)row * DIM + 4 * lane) = o;
        float dx = e.x - zv.x, dy = e.y - zv.y, dz = e.z - zv.z, dw = e.w - zv.w;
        acc += dx * dx + dy * dy + dz * dz + dw * dw;
        if (lane == 0) atomicAdd(counts + ix, 1);
    }
    red[t] = acc;
    __syncthreads();
    #pragma unroll
    for (int o = 128; o > 0; o >>= 1) { if (t < o) red[t] += red[t + o]; __syncthreads(); }
    if (t == 0) partials[blockIdx.x] = red[0];
}

// ---- K4: final loss reduce ----
__global__ void k_loss(const float* __restrict__ partials, float* __restrict__ out_loss) {
    __shared__ float red[256];
    int t = threadIdx.x;
    float a = 0.f;
    for (int i = t; i < 2048; i += 256) a += partials[i];
    red[t] = a;
    __syncthreads();
    #pragma unroll
    for (int o = 128; o > 0; o >>= 1) { if (t < o) red[t] += red[t + o]; __syncthreads(); }
    if (t == 0) out_loss[0] = 1.25f * (red[0] / 33554432.0f);
}

// ---- K5: finalize new_embedding + new_embed_prob ----
__global__ void k_final(const float* __restrict__ z, const float* __restrict__ emb,
                        const float* __restrict__ eprob, const int* __restrict__ counts,
                        const u64* __restrict__ colmax,
                        float* __restrict__ out_emb, float* __restrict__ out_prob) {
    int k = blockIdx.x, lane = threadIdx.x;
    int r = (int)(~(u32)(colmax[k] & 0xFFFFFFFFull));
    float avg = (float)counts[k] * (1.0f / (float)NROWS);
    float nep = eprob[k] * 0.99f + avg * 0.01f;
    float reinit = expf(-(((nep * 2048.0f) * 10.0f) / 0.01f) - 0.001f);
    float4 ev = *(const float4*)(emb + (size_t)k * DIM + 4 * lane);
    float4 zv = *(const float4*)(z + (size_t)r * DIM + 4 * lane);
    float4 o;
    o.x = ev.x * (1.f - reinit) + zv.x * reinit;
    o.y = ev.y * (1.f - reinit) + zv.y * reinit;
    o.z = ev.z * (1.f - reinit) + zv.z * reinit;
    o.w = ev.w * (1.f - reinit) + zv.w * reinit;
    *(float4*)(out_emb + (size_t)k * DIM + 4 * lane) = o;
    if (lane == 0) out_prob[k] = nep;
}

extern "C" void kernel_launch(void* const* d_in, const int* in_sizes, int n_in,
                              void* d_out, int out_size, void* d_ws, size_t ws_size,
                              hipStream_t stream) {
    const float* z   = (const float*)d_in[0];
    const float* emb = (const float*)d_in[1];
    const float* epr = (const float*)d_in[2];

    float* out      = (float*)d_out;
    float* out_zq   = out;
    float* out_loss = out + (size_t)NROWS * DIM;
    float* out_emb  = out_loss + 1;
    float* out_prob = out_emb + (size_t)KCB * DIM;

    // z_pk (32 planes x NROWS x 8 u16 = 64 MB) aliases the zq region of d_out;
    // overwritten by k_gather after k_mfma consumed it.
    u16* zpk = (u16*)d_out;

    char* ws = (char*)d_ws;
    u16*   epk    = (u16*)  (ws + 0);          // 1 MB used (32 planes)
    u64*   rowmax = (u64*)  (ws + 2097152);    // 1 MB
    u64*   colmax = (u64*)  (ws + 3145728);    // 16 KB
    int*   counts = (int*)  (ws + 3162112);    // 8 KB
    float* parts  = (float*)(ws + 3170304);    // 8 KB

    hipMemsetAsync(rowmax, 0, 1048576 + 16384 + 8192, stream);

    k_prep<<<NROWS / 64, 256, 0, stream>>>(z, zpk, (size_t)NROWS * 8);
    k_prep<<<KCB / 64, 256, 0, stream>>>(emb, epk, (size_t)KCB * 8);
    k_mfma<<<(NROWS / 128) * (KCB / 128), 256, 0, stream>>>(zpk, epk, rowmax, colmax);
    k_gather<<<NROWS / 64, 256, 0, stream>>>(z, emb, rowmax, out_zq, counts, parts);
    k_loss<<<1, 256, 0, stream>>>(parts, out_loss);
    k_final<<<KCB, 64, 0, stream>>>(z, emb, epr, counts, colmax, out_emb, out_prob);
}

// Round 21
// 402.434 us; speedup vs baseline: 2.0300x; 1.1604x over previous
//
#include <hip/hip_runtime.h>

#define NROWS 131072
#define KCB   2048
#define DIM   256

typedef unsigned int u32;
typedef unsigned long long u64;
typedef unsigned short u16;
typedef __attribute__((ext_vector_type(8))) short short8;
typedef __attribute__((ext_vector_type(16))) float f32x16;

__device__ __forceinline__ u32 fkey(float f) {
    u32 b = __float_as_uint(f);
    return (b & 0x80000000u) ? ~b : (b | 0x80000000u);
}
__device__ __forceinline__ u16 bf_rne(float x) {
    u32 u = __float_as_uint(x);
    return (u16)((u + 0x7FFFu + ((u >> 16) & 1u)) >> 16);
}
__device__ __forceinline__ void gload16(const u16* src, u16* dst) {
    __builtin_amdgcn_global_load_lds(
        (const __attribute__((address_space(1))) void*)src,
        (__attribute__((address_space(3))) void*)dst, 16, 0, 0);
}

// ---- K0: normalize rows, round to bf16, write plane-major layout
// dst[plane][row][8], planes 0..31 (k-octets). (r19-verified)
__global__ void k_prep(const float* __restrict__ src, u16* __restrict__ dst,
                       size_t planeStride) {
    __shared__ u16 L[64][264];
    const int t = threadIdx.x, w = t >> 6, lane = t & 63;
    const int rbase = blockIdx.x * 64;

    #pragma unroll
    for (int i = 0; i < 16; ++i) {
        int row = rbase + w * 16 + i;
        float4 v = *(const float4*)(src + (size_t)row * DIM + 4 * lane);
        float ss = v.x * v.x + v.y * v.y + v.z * v.z + v.w * v.w;
        #pragma unroll
        for (int o = 32; o > 0; o >>= 1) ss += __shfl_down(ss, o, 64);
        ss = __shfl(ss, 0, 64);
        float inv = 1.0f / fmaxf(sqrtf(ss), 1e-12f);
        u16 hh[4] = {bf_rne(v.x * inv), bf_rne(v.y * inv),
                     bf_rne(v.z * inv), bf_rne(v.w * inv)};
        *(ushort4*)&L[w * 16 + i][4 * lane] = make_ushort4(hh[0], hh[1], hh[2], hh[3]);
    }
    __syncthreads();
    #pragma unroll
    for (int q = 0; q < 8; ++q) {
        int c = q * 256 + t;
        int kb = c >> 6, r = c & 63;
        short8 val = *(const short8*)&L[r][kb * 8];
        *(short8*)(dst + (size_t)kb * planeStride + (size_t)(rbase + r) * 8) = val;
    }
}

// ---- K2: MFMA GEMM + twin transposed accumulator.
// 128x128 tile, 8 waves (2 row x 4 col), wave-tile 64x32, BK=32, 8 chunks.
// Per chunk per wave: 6 ds_read + 8 MFMA (4 for acc = d, 4 for acc2 = d^T on
// the SAME fragments). Both argmaxes become lane-local scans + one
// shfl_xor(32) merge -- no butterfly. r20's 2-deep counted-vmcnt pipeline.
__launch_bounds__(512, 4)
__global__ void k_mfma(const u16* __restrict__ zpk, const u16* __restrict__ epk,
                       u64* __restrict__ rowmax, u64* __restrict__ colmax) {
    // per buffer (u16 idx): A [0,4096) = [4 planes][128 rows][8]; B [4096,8192)
    __shared__ __align__(16) u16 lds[2][8192];
    const int t = threadIdx.x;
    const int lane = t & 63, l31 = lane & 31, lhi = lane >> 5;
    const int w = t >> 6, wr = w >> 2, wc = w & 3;

    // bijective XCD swizzle (nwg=16384, 2048/XCD)
    const int swz = (blockIdx.x & 7) * 2048 + (blockIdx.x >> 3);
    const int brow = (swz >> 4) * 128;
    const int bcol = (swz & 15) * 128;

    const size_t ZPS = (size_t)NROWS * 8;   // z plane stride (u16)
    const size_t EPS = (size_t)KCB * 8;     // e plane stride (u16)

    f32x16 acc[2];    // d: rows 64 (reg axis), cols 32 (lane axis)
    f32x16 acc2[2];   // d^T: rows = e-cols (reg axis), cols = z-rows (lane axis)
    #pragma unroll
    for (int i = 0; i < 2; ++i)
        #pragma unroll
        for (int r = 0; r < 16; ++r) { acc[i][r] = 0.f; acc2[i][r] = 0.f; }

    // ---- hoisted staging sources (chunk 0); chunk c adds 4c*planeStride ----
    const int ph = t >> 7;          // plane 0..3 for this thread
    const int rr = t & 127;         // row within tile
    const u16* sA = zpk + (size_t)ph * ZPS + (size_t)(brow + rr) * 8;
    const u16* sB = epk + (size_t)ph * EPS + (size_t)(bcol + rr) * 8;
    const int dA = t * 8, dB = 4096 + t * 8;

    // ---- precomputed fragment LDS offsets (u16 idx) ----
    int aK0[2], aK1[2];
    #pragma unroll
    for (int i = 0; i < 2; ++i) {
        int r = wr * 64 + i * 32 + l31;
        aK0[i] = (lhi * 128 + r) * 8;
        aK1[i] = ((2 + lhi) * 128 + r) * 8;
    }
    const int bK0 = 4096 + (lhi * 128 + wc * 32 + l31) * 8;
    const int bK1 = 4096 + ((2 + lhi) * 128 + wc * 32 + l31) * 8;

    auto stage = [&](int b, int c) {
        const size_t oz = (size_t)(4 * c) * ZPS;
        const size_t oe = (size_t)(4 * c) * EPS;
        gload16(sA + oz, &lds[b][dA]);
        gload16(sB + oe, &lds[b][dB]);
    };

    // prologue: 2-deep prefetch (2 loads per stage per thread)
    stage(0, 0);
    stage(1, 1);
    asm volatile("s_waitcnt vmcnt(2)" ::: "memory");   // chunk 0 landed
    __builtin_amdgcn_s_barrier();

    #pragma unroll
    for (int c = 0; c < 8; ++c) {
        const int b = c & 1;

        short8 z0[2], z1[2], e0, e1;
        #pragma unroll
        for (int i = 0; i < 2; ++i) {
            z0[i] = *(const short8*)&lds[b][aK0[i]];
            z1[i] = *(const short8*)&lds[b][aK1[i]];
        }
        e0 = *(const short8*)&lds[b][bK0];
        e1 = *(const short8*)&lds[b][bK1];

        __builtin_amdgcn_s_setprio(1);
        #pragma unroll
        for (int i = 0; i < 2; ++i)
            acc[i] = __builtin_amdgcn_mfma_f32_32x32x16_bf16(z0[i], e0, acc[i], 0, 0, 0);
        #pragma unroll
        for (int i = 0; i < 2; ++i)
            acc[i] = __builtin_amdgcn_mfma_f32_32x32x16_bf16(z1[i], e1, acc[i], 0, 0, 0);
        #pragma unroll
        for (int i = 0; i < 2; ++i)
            acc2[i] = __builtin_amdgcn_mfma_f32_32x32x16_bf16(e0, z0[i], acc2[i], 0, 0, 0);
        #pragma unroll
        for (int i = 0; i < 2; ++i)
            acc2[i] = __builtin_amdgcn_mfma_f32_32x32x16_bf16(e1, z1[i], acc2[i], 0, 0, 0);
        __builtin_amdgcn_s_setprio(0);

        __builtin_amdgcn_s_barrier();                  // all waves done reading buf b
        if (c + 2 < 8) {
            stage(b, c + 2);
            asm volatile("s_waitcnt vmcnt(2)" ::: "memory");   // chunk c+1 landed
        } else if (c == 6) {
            asm volatile("s_waitcnt vmcnt(0)" ::: "memory");   // chunk 7 landed
        }
        __builtin_amdgcn_s_barrier();
    }

    // ---- epilogue: both argmaxes lane-local (tie: val desc, index asc) ----
    float2* colred = (float2*)&lds[0][0];      // [2 wr][128 cols]  bytes 0..2047
    float2* rowred = (float2*)&lds[0][1024];   // [4 wc][128 rows]  bytes 2048..6143

    // col argmax from acc: fixed col (lane), scan rows (regs), merge halves.
    {
        float bv = -3.4e38f; int brw = 0x7FFFFFFF;
        #pragma unroll
        for (int i = 0; i < 2; ++i)
            #pragma unroll
            for (int r = 0; r < 16; ++r) {
                float v = acc[i][r];
                int rg = brow + wr * 64 + i * 32 + (r & 3) + 8 * (r >> 2) + 4 * lhi;
                if (v > bv || (v == bv && rg < brw)) { bv = v; brw = rg; }
            }
        float ov = __shfl_xor(bv, 32); int orw = __shfl_xor(brw, 32);
        if (ov > bv || (ov == bv && orw < brw)) { bv = ov; brw = orw; }
        if (lane < 32) colred[wr * 128 + wc * 32 + l31] = make_float2(bv, __int_as_float(brw));
    }

    // row argmax from acc2: fixed z-row (lane), scan e-cols (regs), merge halves.
    #pragma unroll
    for (int i = 0; i < 2; ++i) {
        float bv = -3.4e38f; int bc = 0x7FFFFFFF;
        #pragma unroll
        for (int r = 0; r < 16; ++r) {
            float v = acc2[i][r];
            int kg = bcol + wc * 32 + (r & 3) + 8 * (r >> 2) + 4 * lhi;
            if (v > bv || (v == bv && kg < bc)) { bv = v; bc = kg; }
        }
        float ov = __shfl_xor(bv, 32); int oc = __shfl_xor(bc, 32);
        if (ov > bv || (ov == bv && oc < bc)) { bv = ov; bc = oc; }
        if (lane < 32) rowred[wc * 128 + wr * 64 + i * 32 + l31] = make_float2(bv, __int_as_float(bc));
    }
    __syncthreads();

    if (t < 128) {
        float2 c0_ = colred[t], c1_ = colred[128 + t];
        float bv = c0_.x; int brw = __float_as_int(c0_.y);
        if (c1_.x > bv || (c1_.x == bv && __float_as_int(c1_.y) < brw)) { bv = c1_.x; brw = __float_as_int(c1_.y); }
        atomicMax(colmax + bcol + t, ((u64)fkey(bv) << 32) | (u64)(~(u32)brw));

        float rv = -3.4e38f; int rc = 0x7FFFFFFF;
        #pragma unroll
        for (int q = 0; q < 4; ++q) {
            float2 e = rowred[q * 128 + t];
            float v = e.x; int c2 = __float_as_int(e.y);
            if (v > rv || (v == rv && c2 < rc)) { rv = v; rc = c2; }
        }
        atomicMax(rowmax + brow + t, ((u64)fkey(rv) << 32) | (u64)(~(u32)rc));
    }
}

// ---- K3: gather z_q, write out0, loss partials, histogram ----
__global__ void k_gather(const float* __restrict__ z, const float* __restrict__ emb,
                         const u64* __restrict__ rowmax, float* __restrict__ zq_out,
                         int* __restrict__ counts, float* __restrict__ partials) {
    __shared__ float red[256];
    int t = threadIdx.x;
    int lane = t & 63, w = t >> 6;
    int base = blockIdx.x * 64;
    float acc = 0.f;
    for (int r = 0; r < 16; ++r) {
        int row = base + w * 16 + r;
        int ix = (int)(~(u32)(rowmax[row] & 0xFFFFFFFFull));
        float4 e  = *(const float4*)(emb + (size_t)ix * DIM + 4 * lane);
        float4 zv = *(const float4*)(z + (size_t)row * DIM + 4 * lane);
        float4 o;
        o.x = zv.x + (e.x - zv.x); o.y = zv.y + (e.y - zv.y);
        o.z = zv.z + (e.z - zv.z); o.w = zv.w + (e.w - zv.w);
        *(float4*)(zq_out + (size_t)row * DIM + 4 * lane) = o;
        float dx = e.x - zv.x, dy = e.y - zv.y, dz = e.z - zv.z, dw = e.w - zv.w;
        acc += dx * dx + dy * dy + dz * dz + dw * dw;
        if (lane == 0) atomicAdd(counts + ix, 1);
    }
    red[t] = acc;
    __syncthreads();
    #pragma unroll
    for (int o = 128; o > 0; o >>= 1) { if (t < o) red[t] += red[t + o]; __syncthreads(); }
    if (t == 0) partials[blockIdx.x] = red[0];
}

// ---- K4: final loss reduce ----
__global__ void k_loss(const float* __restrict__ partials, float* __restrict__ out_loss) {
    __shared__ float red[256];
    int t = threadIdx.x;
    float a = 0.f;
    for (int i = t; i < 2048; i += 256) a += partials[i];
    red[t] = a;
    __syncthreads();
    #pragma unroll
    for (int o = 128; o > 0; o >>= 1) { if (t < o) red[t] += red[t + o]; __syncthreads(); }
    if (t == 0) out_loss[0] = 1.25f * (red[0] / 33554432.0f);
}

// ---- K5: finalize new_embedding + new_embed_prob ----
__global__ void k_final(const float* __restrict__ z, const float* __restrict__ emb,
                        const float* __restrict__ eprob, const int* __restrict__ counts,
                        const u64* __restrict__ colmax,
                        float* __restrict__ out_emb, float* __restrict__ out_prob) {
    int k = blockIdx.x, lane = threadIdx.x;
    int r = (int)(~(u32)(colmax[k] & 0xFFFFFFFFull));
    float avg = (float)counts[k] * (1.0f / (float)NROWS);
    float nep = eprob[k] * 0.99f + avg * 0.01f;
    float reinit = expf(-(((nep * 2048.0f) * 10.0f) / 0.01f) - 0.001f);
    float4 ev = *(const float4*)(emb + (size_t)k * DIM + 4 * lane);
    float4 zv = *(const float4*)(z + (size_t)r * DIM + 4 * lane);
    float4 o;
    o.x = ev.x * (1.f - reinit) + zv.x * reinit;
    o.y = ev.y * (1.f - reinit) + zv.y * reinit;
    o.z = ev.z * (1.f - reinit) + zv.z * reinit;
    o.w = ev.w * (1.f - reinit) + zv.w * reinit;
    *(float4*)(out_emb + (size_t)k * DIM + 4 * lane) = o;
    if (lane == 0) out_prob[k] = nep;
}

extern "C" void kernel_launch(void* const* d_in, const int* in_sizes, int n_in,
                              void* d_out, int out_size, void* d_ws, size_t ws_size,
                              hipStream_t stream) {
    const float* z   = (const float*)d_in[0];
    const float* emb = (const float*)d_in[1];
    const float* epr = (const float*)d_in[2];

    float* out      = (float*)d_out;
    float* out_zq   = out;
    float* out_loss = out + (size_t)NROWS * DIM;
    float* out_emb  = out_loss + 1;
    float* out_prob = out_emb + (size_t)KCB * DIM;

    // z_pk (32 planes x NROWS x 8 u16 = 64 MB) aliases the zq region of d_out;
    // overwritten by k_gather after k_mfma consumed it.
    u16* zpk = (u16*)d_out;

    char* ws = (char*)d_ws;
    u16*   epk    = (u16*)  (ws + 0);          // 1 MB used (32 planes)
    u64*   rowmax = (u64*)  (ws + 2097152);    // 1 MB
    u64*   colmax = (u64*)  (ws + 3145728);    // 16 KB
    int*   counts = (int*)  (ws + 3162112);    // 8 KB
    float* parts  = (float*)(ws + 3170304);    // 8 KB

    hipMemsetAsync(rowmax, 0, 1048576 + 16384 + 8192, stream);

    k_prep<<<NROWS / 64, 256, 0, stream>>>(z, zpk, (size_t)NROWS * 8);
    k_prep<<<KCB / 64, 256, 0, stream>>>(emb, epk, (size_t)KCB * 8);
    k_mfma<<<(NROWS / 128) * (KCB / 128), 512, 0, stream>>>(zpk, epk, rowmax, colmax);
    k_gather<<<NROWS / 64, 256, 0, stream>>>(z, emb, rowmax, out_zq, counts, parts);
    k_loss<<<1, 256, 0, stream>>>(parts, out_loss);
    k_final<<<KCB, 64, 0, stream>>>(z, emb, epr, counts, colmax, out_emb, out_prob);
}

// Round 22
// 402.394 us; speedup vs baseline: 2.0302x; 1.0001x over previous
//
#include <hip/hip_runtime.h>

#define NROWS 131072
#define KCB   2048
#define DIM   256

typedef unsigned int u32;
typedef unsigned long long u64;
typedef unsigned short u16;
typedef __attribute__((ext_vector_type(8))) short short8;
typedef __attribute__((ext_vector_type(16))) float f32x16;

__device__ __forceinline__ u32 fkey(float f) {
    u32 b = __float_as_uint(f);
    return (b & 0x80000000u) ? ~b : (b | 0x80000000u);
}
__device__ __forceinline__ u16 bf_rne(float x) {
    u32 u = __float_as_uint(x);
    return (u16)((u + 0x7FFFu + ((u >> 16) & 1u)) >> 16);
}
__device__ __forceinline__ void gload16(const u16* src, u16* dst) {
    __builtin_amdgcn_global_load_lds(
        (const __attribute__((address_space(1))) void*)src,
        (__attribute__((address_space(3))) void*)dst, 16, 0, 0);
}

// ---- K0: normalize rows, round to bf16, write plane-major layout
// dst[plane][row][8], planes 0..31 (k-octets). (r19-verified)
__global__ void k_prep(const float* __restrict__ src, u16* __restrict__ dst,
                       size_t planeStride) {
    __shared__ u16 L[64][264];
    const int t = threadIdx.x, w = t >> 6, lane = t & 63;
    const int rbase = blockIdx.x * 64;

    #pragma unroll
    for (int i = 0; i < 16; ++i) {
        int row = rbase + w * 16 + i;
        float4 v = *(const float4*)(src + (size_t)row * DIM + 4 * lane);
        float ss = v.x * v.x + v.y * v.y + v.z * v.z + v.w * v.w;
        #pragma unroll
        for (int o = 32; o > 0; o >>= 1) ss += __shfl_down(ss, o, 64);
        ss = __shfl(ss, 0, 64);
        float inv = 1.0f / fmaxf(sqrtf(ss), 1e-12f);
        u16 hh[4] = {bf_rne(v.x * inv), bf_rne(v.y * inv),
                     bf_rne(v.z * inv), bf_rne(v.w * inv)};
        *(ushort4*)&L[w * 16 + i][4 * lane] = make_ushort4(hh[0], hh[1], hh[2], hh[3]);
    }
    __syncthreads();
    #pragma unroll
    for (int q = 0; q < 8; ++q) {
        int c = q * 256 + t;
        int kb = c >> 6, r = c & 63;
        short8 val = *(const short8*)&L[r][kb * 8];
        *(short8*)(dst + (size_t)kb * planeStride + (size_t)(rbase + r) * 8) = val;
    }
}

// ---- K2: MFMA GEMM + twin transposed accumulator, BK=64 (4 chunks).
// 128x128 tile, 8 waves (2 row x 4 col), wave-tile 64x32. Per chunk per wave:
// 12 ds_read + 16 MFMA, slice-by-slice (4 k-slices, 3 frags live). LDS
// 2 x 32 KB = 64 KB/block -> 2 blocks/CU (4 waves/SIMD). 2-deep counted-vmcnt.
// Per-accumulator FP order identical to r21 (absmax must stay 0.003082275).
__launch_bounds__(512, 4)
__global__ void k_mfma(const u16* __restrict__ zpk, const u16* __restrict__ epk,
                       u64* __restrict__ rowmax, u64* __restrict__ colmax) {
    // per buffer (u16 idx): A [0,8192) = [8 planes][128 rows][8];
    //                       B [8192,16384) = [8 planes][128 rows][8]
    // plane p of chunk c = global k-octet 8c+p.
    __shared__ __align__(16) u16 lds[2][16384];
    const int t = threadIdx.x;
    const int lane = t & 63, l31 = lane & 31, lhi = lane >> 5;
    const int w = t >> 6, wr = w >> 2, wc = w & 3;

    // bijective XCD swizzle (nwg=16384, 2048/XCD)
    const int swz = (blockIdx.x & 7) * 2048 + (blockIdx.x >> 3);
    const int brow = (swz >> 4) * 128;
    const int bcol = (swz & 15) * 128;

    const size_t ZPS = (size_t)NROWS * 8;   // z plane stride (u16)
    const size_t EPS = (size_t)KCB * 8;     // e plane stride (u16)

    f32x16 acc[2];    // d: rows (reg axis), cols (lane axis)
    f32x16 acc2[2];   // d^T
    #pragma unroll
    for (int i = 0; i < 2; ++i)
        #pragma unroll
        for (int r = 0; r < 16; ++r) { acc[i][r] = 0.f; acc2[i][r] = 0.f; }

    // ---- hoisted staging sources (chunk 0); chunk c adds 8c*planeStride ----
    const int ph = t >> 7;          // plane sub-index 0..3 for this thread
    const int rr = t & 127;         // row within tile
    const u16* sA0 = zpk + (size_t)ph * ZPS + (size_t)(brow + rr) * 8;         // planes 0..3
    const u16* sA1 = zpk + (size_t)(4 + ph) * ZPS + (size_t)(brow + rr) * 8;   // planes 4..7
    const u16* sB0 = epk + (size_t)ph * EPS + (size_t)(bcol + rr) * 8;
    const u16* sB1 = epk + (size_t)(4 + ph) * EPS + (size_t)(bcol + rr) * 8;
    const int dA0 = t * 8, dA1 = (512 + t) * 8;
    const int dB0 = 8192 + t * 8, dB1 = 8192 + (512 + t) * 8;

    // ---- precomputed fragment LDS offsets (u16 idx), slice s: planes 2s+lhi ----
    int aOff[4][2], bOff[4];
    #pragma unroll
    for (int s = 0; s < 4; ++s) {
        #pragma unroll
        for (int i = 0; i < 2; ++i)
            aOff[s][i] = ((2 * s + lhi) * 128 + wr * 64 + i * 32 + l31) * 8;
        bOff[s] = 8192 + ((2 * s + lhi) * 128 + wc * 32 + l31) * 8;
    }

    auto stage = [&](int b, int c) {
        const size_t oz = (size_t)(8 * c) * ZPS;
        const size_t oe = (size_t)(8 * c) * EPS;
        gload16(sA0 + oz, &lds[b][dA0]);
        gload16(sA1 + oz, &lds[b][dA1]);
        gload16(sB0 + oe, &lds[b][dB0]);
        gload16(sB1 + oe, &lds[b][dB1]);
    };

    // prologue: 2-deep prefetch (4 loads per stage per thread)
    stage(0, 0);
    stage(1, 1);
    asm volatile("s_waitcnt vmcnt(4)" ::: "memory");   // chunk 0 landed
    __builtin_amdgcn_s_barrier();

    #pragma unroll
    for (int c = 0; c < 4; ++c) {
        const int b = c & 1;

        __builtin_amdgcn_s_setprio(1);
        #pragma unroll
        for (int s = 0; s < 4; ++s) {
            short8 z0 = *(const short8*)&lds[b][aOff[s][0]];
            short8 z1 = *(const short8*)&lds[b][aOff[s][1]];
            short8 ee = *(const short8*)&lds[b][bOff[s]];
            acc[0]  = __builtin_amdgcn_mfma_f32_32x32x16_bf16(z0, ee, acc[0], 0, 0, 0);
            acc[1]  = __builtin_amdgcn_mfma_f32_32x32x16_bf16(z1, ee, acc[1], 0, 0, 0);
            acc2[0] = __builtin_amdgcn_mfma_f32_32x32x16_bf16(ee, z0, acc2[0], 0, 0, 0);
            acc2[1] = __builtin_amdgcn_mfma_f32_32x32x16_bf16(ee, z1, acc2[1], 0, 0, 0);
        }
        __builtin_amdgcn_s_setprio(0);

        __builtin_amdgcn_s_barrier();                  // all waves done reading buf b
        if (c + 2 < 4) {
            stage(b, c + 2);
            asm volatile("s_waitcnt vmcnt(4)" ::: "memory");   // chunk c+1 landed
        } else if (c == 2) {
            asm volatile("s_waitcnt vmcnt(0)" ::: "memory");   // chunk 3 landed
        }
        __builtin_amdgcn_s_barrier();
    }

    // ---- epilogue: both argmaxes lane-local (tie: val desc, index asc) ----
    float2* colred = (float2*)&lds[0][0];      // [2 wr][128 cols]
    float2* rowred = (float2*)&lds[0][1024];   // [4 wc][128 rows]

    {
        float bv = -3.4e38f; int brw = 0x7FFFFFFF;
        #pragma unroll
        for (int i = 0; i < 2; ++i)
            #pragma unroll
            for (int r = 0; r < 16; ++r) {
                float v = acc[i][r];
                int rg = brow + wr * 64 + i * 32 + (r & 3) + 8 * (r >> 2) + 4 * lhi;
                if (v > bv || (v == bv && rg < brw)) { bv = v; brw = rg; }
            }
        float ov = __shfl_xor(bv, 32); int orw = __shfl_xor(brw, 32);
        if (ov > bv || (ov == bv && orw < brw)) { bv = ov; brw = orw; }
        if (lane < 32) colred[wr * 128 + wc * 32 + l31] = make_float2(bv, __int_as_float(brw));
    }

    #pragma unroll
    for (int i = 0; i < 2; ++i) {
        float bv = -3.4e38f; int bc = 0x7FFFFFFF;
        #pragma unroll
        for (int r = 0; r < 16; ++r) {
            float v = acc2[i][r];
            int kg = bcol + wc * 32 + (r & 3) + 8 * (r >> 2) + 4 * lhi;
            if (v > bv || (v == bv && kg < bc)) { bv = v; bc = kg; }
        }
        float ov = __shfl_xor(bv, 32); int oc = __shfl_xor(bc, 32);
        if (ov > bv || (ov == bv && oc < bc)) { bv = ov; bc = oc; }
        if (lane < 32) rowred[wc * 128 + wr * 64 + i * 32 + l31] = make_float2(bv, __int_as_float(bc));
    }
    __syncthreads();

    if (t < 128) {
        float2 c0_ = colred[t], c1_ = colred[128 + t];
        float bv = c0_.x; int brw = __float_as_int(c0_.y);
        if (c1_.x > bv || (c1_.x == bv && __float_as_int(c1_.y) < brw)) { bv = c1_.x; brw = __float_as_int(c1_.y); }
        atomicMax(colmax + bcol + t, ((u64)fkey(bv) << 32) | (u64)(~(u32)brw));

        float rv = -3.4e38f; int rc = 0x7FFFFFFF;
        #pragma unroll
        for (int q = 0; q < 4; ++q) {
            float2 e = rowred[q * 128 + t];
            float v = e.x; int c2 = __float_as_int(e.y);
            if (v > rv || (v == rv && c2 < rc)) { rv = v; rc = c2; }
        }
        atomicMax(rowmax + brow + t, ((u64)fkey(rv) << 32) | (u64)(~(u32)rc));
    }
}

// ---- K3: gather z_q, write out0, loss partials, histogram ----
__global__ void k_gather(const float* __restrict__ z, const float* __restrict__ emb,
                         const u64* __restrict__ rowmax, float* __restrict__ zq_out,
                         int* __restrict__ counts, float* __restrict__ partials) {
    __shared__ float red[256];
    int t = threadIdx.x;
    int lane = t & 63, w = t >> 6;
    int base = blockIdx.x * 64;
    float acc = 0.f;
    for (int r = 0; r < 16; ++r) {
        int row = base + w * 16 + r;
        int ix = (int)(~(u32)(rowmax[row] & 0xFFFFFFFFull));
        float4 e  = *(const float4*)(emb + (size_t)ix * DIM + 4 * lane);
        float4 zv = *(const float4*)(z + (size_t)row * DIM + 4 * lane);
        float4 o;
        o.x = zv.x + (e.x - zv.x); o.y = zv.y + (e.y - zv.y);
        o.z = zv.z + (e.z - zv.z); o.w = zv.w + (e.w - zv.w);
        *(float4*)(zq_out + (size_t)row * DIM + 4 * lane) = o;
        float dx = e.x - zv.x, dy = e.y - zv.y, dz = e.z - zv.z, dw = e.w - zv.w;
        acc += dx * dx + dy * dy + dz * dz + dw * dw;
        if (lane == 0) atomicAdd(counts + ix, 1);
    }
    red[t] = acc;
    __syncthreads();
    #pragma unroll
    for (int o = 128; o > 0; o >>= 1) { if (t < o) red[t] += red[t + o]; __syncthreads(); }
    if (t == 0) partials[blockIdx.x] = red[0];
}

// ---- K4: final loss reduce ----
__global__ void k_loss(const float* __restrict__ partials, float* __restrict__ out_loss) {
    __shared__ float red[256];
    int t = threadIdx.x;
    float a = 0.f;
    for (int i = t; i < 2048; i += 256) a += partials[i];
    red[t] = a;
    __syncthreads();
    #pragma unroll
    for (int o = 128; o > 0; o >>= 1) { if (t < o) red[t] += red[t + o]; __syncthreads(); }
    if (t == 0) out_loss[0] = 1.25f * (red[0] / 33554432.0f);
}

// ---- K5: finalize new_embedding + new_embed_prob ----
__global__ void k_final(const float* __restrict__ z, const float* __restrict__ emb,
                        const float* __restrict__ eprob, const int* __restrict__ counts,
                        const u64* __restrict__ colmax,
                        float* __restrict__ out_emb, float* __restrict__ out_prob) {
    int k = blockIdx.x, lane = threadIdx.x;
    int r = (int)(~(u32)(colmax[k] & 0xFFFFFFFFull));
    float avg = (float)counts[k] * (1.0f / (float)NROWS);
    float nep = eprob[k] * 0.99f + avg * 0.01f;
    float reinit = expf(-(((nep * 2048.0f) * 10.0f) / 0.01f) - 0.001f);
    float4 ev = *(const float4*)(emb + (size_t)k * DIM + 4 * lane);
    float4 zv = *(const float4*)(z + (size_t)r * DIM + 4 * lane);
    float4 o;
    o.x = ev.x * (1.f - reinit) + zv.x * reinit;
    o.y = ev.y * (1.f - reinit) + zv.y * reinit;
    o.z = ev.z * (1.f - reinit) + zv.z * reinit;
    o.w = ev.w * (1.f - reinit) + zv.w * reinit;
    *(float4*)(out_emb + (size_t)k * DIM + 4 * lane) = o;
    if (lane == 0) out_prob[k] = nep;
}

extern "C" void kernel_launch(void* const* d_in, const int* in_sizes, int n_in,
                              void* d_out, int out_size, void* d_ws, size_t ws_size,
                              hipStream_t stream) {
    const float* z   = (const float*)d_in[0];
    const float* emb = (const float*)d_in[1];
    const float* epr = (const float*)d_in[2];

    float* out      = (float*)d_out;
    float* out_zq   = out;
    float* out_loss = out + (size_t)NROWS * DIM;
    float* out_emb  = out_loss + 1;
    float* out_prob = out_emb + (size_t)KCB * DIM;

    // z_pk (32 planes x NROWS x 8 u16 = 64 MB) aliases the zq region of d_out;
    // overwritten by k_gather after k_mfma consumed it.
    u16* zpk = (u16*)d_out;

    char* ws = (char*)d_ws;
    u16*   epk    = (u16*)  (ws + 0);          // 1 MB used (32 planes)
    u64*   rowmax = (u64*)  (ws + 2097152);    // 1 MB
    u64*   colmax = (u64*)  (ws + 3145728);    // 16 KB
    int*   counts = (int*)  (ws + 3162112);    // 8 KB
    float* parts  = (float*)(ws + 3170304);    // 8 KB

    hipMemsetAsync(rowmax, 0, 1048576 + 16384 + 8192, stream);

    k_prep<<<NROWS / 64, 256, 0, stream>>>(z, zpk, (size_t)NROWS * 8);
    k_prep<<<KCB / 64, 256, 0, stream>>>(emb, epk, (size_t)KCB * 8);
    k_mfma<<<(NROWS / 128) * (KCB / 128), 512, 0, stream>>>(zpk, epk, rowmax, colmax);
    k_gather<<<NROWS / 64, 256, 0, stream>>>(z, emb, rowmax, out_zq, counts, parts);
    k_loss<<<1, 256, 0, stream>>>(parts, out_loss);
    k_final<<<KCB, 64, 0, stream>>>(z, emb, epr, counts, colmax, out_emb, out_prob);
}